// Round 1
// 825.340 us; speedup vs baseline: 1.0845x; 1.0845x over previous
//
#include <hip/hip_runtime.h>
#include <stdint.h>
#include <math.h>

#define THREADS 256
#define NBINS   2048
#define SORTN   2048          // per-image post-cutoff cap (same as previous CAP)
#define PRECAP  65536         // per-image unfiltered candidate cap; expected ~61.2k (+18 sigma slack)
#define C_CLS   30
#define H_      128
#define W_      128
#define HW_     (H_*W_)            // 16384
#define PER_IMG (C_CLS*HW_)        // 491520 (divisible by 1024 -> block-uniform image id)
#define TH      0.3f
#define XLO     -0.8473f           // conservative logit pre-filter (< true f32 boundary -0.847297)
#define BIN_LO  -0.85f
#define BIN_HI  3.35f
#define BIN_SCALE ((float)NBINS / (BIN_HI - BIN_LO))

// exact-as-before sigmoid (f64 -> correctly-rounded f32); only used in decode (16k calls)
__device__ __forceinline__ float sigmoid_rn(float x) {
    return (float)(1.0 / (1.0 + exp(-(double)x)));
}

__device__ __forceinline__ int bin_of_x(float x) {
    int b = (int)((x - BIN_LO) * BIN_SCALE);
    if (b < 0) b = 0;
    if (b > NBINS - 1) b = NBINS - 1;
    return b;
}

// monotone float -> uint map (sign-flip trick); larger logit => larger key
__device__ __forceinline__ unsigned mapf(float x) {
    unsigned u = __float_as_uint(x);
    return (u & 0x80000000u) ? ~u : (u ^ 0x80000000u);
}
__device__ __forceinline__ float unmapf(unsigned m) {
    unsigned u = (m & 0x80000000u) ? (m ^ 0x80000000u) : ~m;
    return __uint_as_float(u);
}

// Pass 1 (fused): single sCls read. Histogram candidate LOGITS AND stage every
// candidate (x > XLO, ~12.4% of elements) as a sortable key. The cutoff filter
// happens later from this 8 MB key list instead of re-reading the 31 MB input.
__global__ void k_hist_collect(const float4* __restrict__ sCls,
                               int* __restrict__ hist,
                               int* __restrict__ cnt,
                               unsigned long long* __restrict__ cand, int tot4) {
    __shared__ int lcnt;
    __shared__ int lbase;
    int i   = blockIdx.x * blockDim.x + threadIdx.x;
    int tid = threadIdx.x;
    // block-uniform image id: 256 threads * 4 elems = 1024 divides PER_IMG
    int n = (int)(((long long)blockIdx.x * blockDim.x * 4) / PER_IMG);
    if (tid == 0) lcnt = 0;
    __syncthreads();

    int nq = 0;
    unsigned long long keys[4];
    int slot0 = 0;
    if (i < tot4) {
        float4 v = sCls[i];
        int ri = i * 4 - n * PER_IMG;
        int* h = hist + n * NBINS;
        float xs[4] = {v.x, v.y, v.z, v.w};
        #pragma unroll
        for (int j = 0; j < 4; ++j) {
            float x = xs[j];
            if (x > XLO) {
                atomicAdd(&h[bin_of_x(x)], 1);
                int rr = ri + j;
                int c  = rr >> 14;            // / HW_
                int hw = rr & (HW_ - 1);
                int idx = hw * C_CLS + c;     // flat index in permuted [HW*C) order
                keys[nq] = ((unsigned long long)mapf(x) << 32) | (unsigned)(~idx);
                ++nq;
            }
        }
        if (nq) slot0 = atomicAdd(&lcnt, nq);   // LDS atomic: cheap
    }
    __syncthreads();
    if (tid == 0) lbase = (lcnt > 0) ? atomicAdd(&cnt[n], lcnt) : 0;
    __syncthreads();
    for (int j = 0; j < nq; ++j) {
        int s = lbase + slot0 + j;
        if (s < PRECAP) cand[(size_t)n * PRECAP + s] = keys[j];
    }
}

// Per image: suffix-sum the histogram, find highest bin b with suffix(b) >= K.
__global__ void k_cutoff(const int* __restrict__ hist, int* __restrict__ cutoffs, int K) {
    __shared__ int suf[NBINS];
    __shared__ int tot[THREADS];
    int n = blockIdx.x, t = threadIdx.x;
    const int CH = NBINS / THREADS;    // 8
    int base = t * CH;
    int run = 0;
    for (int i = CH - 1; i >= 0; --i) {
        run += hist[n * NBINS + base + i];
        suf[base + i] = run;
    }
    int myTot = run;
    tot[t] = run;
    __syncthreads();
    for (int d = 1; d < THREADS; d <<= 1) {
        int v = (t + d < THREADS) ? tot[t + d] : 0;
        __syncthreads();
        tot[t] += v;
        __syncthreads();
    }
    int add = tot[t] - myTot;
    for (int i = 0; i < CH; ++i) suf[base + i] += add;
    __syncthreads();
    if (t == 0 && suf[0] < K) cutoffs[n] = 0;
    for (int i = 0; i < CH; ++i) {
        int b = base + i;
        int sb = suf[b];
        int sb1 = (b + 1 < NBINS) ? suf[b + 1] : 0;
        if (sb >= K && sb1 < K) cutoffs[n] = b;
    }
}

// Pass 3: per image, filter staged candidates by cutoff bin (recomputed from the
// bijectively-stored logit -> identical predicate to before), compact into LDS,
// bitonic-sort descending, emit the sorted top-K keys.
__global__ __launch_bounds__(1024) void k_sort(
        const unsigned long long* __restrict__ cand,
        const int* __restrict__ cnt,
        const int* __restrict__ cutoffs,
        unsigned long long* __restrict__ topk, int K) {
    __shared__ unsigned long long a[SORTN];
    __shared__ int lcnt;
    int n = blockIdx.x, t = threadIdx.x;
    if (t == 0) lcnt = 0;
    for (int i = t; i < SORTN; i += blockDim.x) a[i] = 0ULL;
    __syncthreads();
    int m = cnt[n]; if (m > PRECAP) m = PRECAP;
    int co = cutoffs[n];
    for (int i = t; i < m; i += blockDim.x) {
        unsigned long long key = cand[(size_t)n * PRECAP + i];
        float x = unmapf((unsigned)(key >> 32));   // exact original logit
        if (bin_of_x(x) >= co) {
            int s = atomicAdd(&lcnt, 1);
            if (s < SORTN) a[s] = key;             // same drop-excess semantics as before
        }
    }
    __syncthreads();
    for (int k = 2; k <= SORTN; k <<= 1) {
        for (int j = k >> 1; j > 0; j >>= 1) {
            for (int i = t; i < SORTN; i += blockDim.x) {
                int l = i ^ j;
                if (l > i) {
                    unsigned long long ai = a[i], al = a[l];
                    bool up = ((i & k) == 0);              // descending overall
                    bool sw = up ? (ai < al) : (ai > al);
                    if (sw) { a[i] = al; a[l] = ai; }
                }
            }
            __syncthreads();
        }
    }
    for (int i = t; i < K; i += blockDim.x) topk[n * SORTN + i] = a[i];
}

// Pass 4: decode, one thread per detection across ~63 blocks so the scattered
// 64KB-strided sReg gather is latency-hidden across many CUs (was 16 blocks).
__global__ void k_decode(const unsigned long long* __restrict__ topk,
                         const float* __restrict__ sReg,
                         const float* __restrict__ anchors,
                         float* __restrict__ out, int N, int K) {
    int i = blockIdx.x * blockDim.x + threadIdx.x;
    if (i >= N * K) return;
    int n = i / K;
    int kk = i - n * K;
    unsigned long long key = topk[n * SORTN + kk];
    float x = unmapf((unsigned)(key >> 32));   // padding key 0 -> NaN -> invalid path
    float s = sigmoid_rn(x);
    float* det    = out;
    float* labels = out + (size_t)N * K * 16;
    float* scores = labels + (size_t)N * K;
    float* drow = det + (size_t)i * 16;
    if (s > TH) {
        int idx = (int)(~(unsigned int)key);
        int loc = idx / C_CLS;
        int c   = idx - loc * C_CLS;
        float a0 = anchors[loc * 4 + 0], a1 = anchors[loc * 4 + 1];
        float a2 = anchors[loc * 4 + 2], a3 = anchors[loc * 4 + 3];
        float wa = a2 - a0, ha = a3 - a1;
        float cx = 0.5f * (a0 + a2), cy = 0.5f * (a1 + a3);
        const float* rbase = sReg + (size_t)((n * C_CLS + c) * 16) * HW_ + loc;
        #pragma unroll
        for (int j = 0; j < 8; ++j)
            drow[j] = rbase[(size_t)j * HW_] * wa + cx;
        #pragma unroll
        for (int j = 0; j < 8; ++j)
            drow[8 + j] = rbase[(size_t)(8 + j) * HW_] * ha + cy;
        labels[i] = (float)(c + 1);
        scores[i] = sqrtf(s);
    } else {
        #pragma unroll
        for (int j = 0; j < 16; ++j) drow[j] = 0.0f;
        labels[i] = 0.0f;
        scores[i] = 0.0f;
    }
}

extern "C" void kernel_launch(void* const* d_in, const int* in_sizes, int n_in,
                              void* d_out, int out_size, void* d_ws, size_t ws_size,
                              hipStream_t stream) {
    const float* sCls    = (const float*)d_in[0];
    const float* sReg    = (const float*)d_in[1];
    const float* anchors = (const float*)d_in[2];
    int tot = in_sizes[0];                 // N*C*H*W
    int N   = tot / PER_IMG;               // 16
    int K   = out_size / (N * 18);         // 1000

    char* ws = (char*)d_ws;
    size_t hist_bytes = (size_t)N * NBINS * sizeof(int);
    int* hist    = (int*)ws;
    int* cnt     = (int*)(ws + hist_bytes);
    int* cutoffs = cnt + N;
    size_t zero_bytes = hist_bytes + 2 * (size_t)N * sizeof(int);
    size_t cand_off = (zero_bytes + 255) & ~(size_t)255;
    unsigned long long* cand = (unsigned long long*)(ws + cand_off);
    size_t topk_off = cand_off + (size_t)N * PRECAP * sizeof(unsigned long long);
    unsigned long long* topk = (unsigned long long*)(ws + topk_off);
    // ws usage: ~8.6 MB total (cand 8 MB + topk 256 KB + hist 128 KB)

    hipMemsetAsync(d_ws, 0, zero_bytes, stream);   // zero hist + cnt + cutoffs

    int tot4 = tot / 4;
    int blocks4 = (tot4 + THREADS - 1) / THREADS;
    k_hist_collect<<<blocks4, THREADS, 0, stream>>>((const float4*)sCls, hist, cnt, cand, tot4);
    k_cutoff<<<N, THREADS, 0, stream>>>(hist, cutoffs, K);
    k_sort<<<N, 1024, 0, stream>>>(cand, cnt, cutoffs, topk, K);
    int nk = N * K;
    k_decode<<<(nk + 255) / 256, 256, 0, stream>>>(topk, sReg, anchors, (float*)d_out, N, K);
}